// Round 10
// baseline (871.501 us; speedup 1.0000x reference)
//
#include <hip/hip_runtime.h>
#include <hip/hip_fp16.h>
#include <math.h>

#define N_NODES   100000
#define N_EDGES   200000
#define NNZ       2000000
#define K_KEEP    1000000
#define BANDCAP   131072
#define TIECAP    4096
// R10: p_ab2 stored fp16 (halves edge_logit's gather bytes). DELTA must now bound
// |p_f32(fp16 table) - p_f64(exact)|: fp16 storage err <=~1e-3/elem -> p err RMS ~3e-4.
// DELTA=2e-3 keeps >=5x margin; rescue (f64 from x, fp16-independent) decides boundaries.
#define DELTA     2.0e-3f
#define SCAN_BLOCKS 196   // ceil(200000/1024)
// band width = 2*DELTA + level-2 bucket (~6e-5) = 4.07e-3 -> u32 map range must cover it.
#define USCALE (4294967296.0 / 8.0e-3)   // band key -> u32 map; band width < 8e-3 guaranteed

#define SC_PASSES 8
#define SC_EPP    (N_EDGES / SC_PASSES)   // 25000 edges per pass (~2MB vj region, fits XCD L2)
#define SC_BLOCKS 2048                    // 256 blocks per pass

// fused-dispatch grid splits
#define CNT_BLOCKS  ((NNZ + 2047) / 2048)        // 977  count_rank blocks (first: critical path)
#define PROJ_BLOCKS ((N_NODES + 63) / 64)        // 1563 proj blocks (64 nodes each)
#define OUT_BLOCKS  ((NNZ / 4 + 255) / 256)      // 1954
#define EOUT_BLOCKS ((N_EDGES + 255) / 256)      // 782

// ---------------- workspace layout (bytes) ----------------
// R10: p_ab2 is now __half2 [N_NODES*32] = 12.8MB (layout a0,b0,a1,b1,... per node row of
// 128B); R9's cntp padding REVERTED (null result: atomic rate, not line contention, is the
// limiter) -> compact edge_cnt in the zero region again, no extra memset.
#define OFF_PAB   ((size_t)0)          // __half2 p_abh [N_NODES*32] 12,800,000
#define OFF_PB32  ((size_t)25600000)   // f32 probs_b [NNZ]        8,000,000 (CSR/p-order probs)
#define OFF_VJ    ((size_t)33600000)   // uint2 vj [NNZ]          16,000,000 (.x=vertex, .y=orig j)
#define OFF_RANK  ((size_t)49600000)   // u32 rank [NNZ] j->rank-in-edge  8,000,000
#define OFF_EOFF  ((size_t)57600000)   // u32 edge_off [N_EDGES+1]   800,004 (sentinel spills
                                       // into the unused OFF_CUR slot)
#define OFF_CUR   ((size_t)58400000)   // (unused; first 4B = edge_off sentinel)
#define OFF_BS    ((size_t)59200000)   // u32 bsums [256]              1,024
#define OFF_BANDP ((size_t)59201024)   // u32 band_p [BANDCAP]       524,288
#define OFF_BANDJ ((size_t)59725312)   // u32 band_j [BANDCAP]       524,288
#define OFF_BANDE ((size_t)60249600)   // u32 band_e [BANDCAP]       524,288
#define OFF_BANDV ((size_t)60773888)   // u32 band_v [BANDCAP]       524,288
#define OFF_BANDK ((size_t)61298176)   // u64 band_key [BANDCAP]   1,048,576
#define OFF_TIEK  ((size_t)62346752)   // u64 tie_k [TIECAP]          32,768
#define OFF_TIEJ  ((size_t)62379520)   // u32 tie_j [TIECAP]          16,384
#define OFF_TIEP  ((size_t)62395904)   // u32 tie_p [TIECAP]          16,384
// --- zero region ---
#define OFF_FLAG  ((size_t)62412288)   // u8  flag [NNZ]           2,000,000 (0 none, 2 selected)
#define OFF_ECNT  ((size_t)64412288)   // u32 edge_cnt [N_EDGES]     800,000 (zeroed by memset)
#define OFF_HIST  ((size_t)65212288)   // u32 hist [4*2048]           32,768
#define OFF_ST    ((size_t)65245056)   // SelState (padded)              256
#define ZERO_OFF  OFF_FLAG
#define ZERO_LEN  ((size_t)(65245312 - 62412288))

// hot atomic counters (n_hi, band_n, tie_n) each on their own 64B line
struct SelState {
    unsigned int B1;        // (unused)
    unsigned int rem1;      // (unused)
    float lo_edge, hi_edge; // band boundaries (written redundantly by bandsel blocks)
    unsigned int bB1;       // (unused)
    unsigned int brem1;     // (unused)
    unsigned int bU0;       // threshold u-bucket base (written by btie block 0)
    unsigned int brem2;     // remaining rank within the u-bucket (written by btie block 0)
    unsigned int _pad0[8];  // -> 64 B
    unsigned int n_hi;      unsigned int _pad1[15];   // own line
    unsigned int band_n;    unsigned int _pad2[15];   // own line
    unsigned int tie_n;     unsigned int _pad3[15];   // own line
};

__device__ __forceinline__ unsigned int band_u32(double key, float lo) {
    double t = (key - (double)lo) * USCALE;
    t = t < 0.0 ? 0.0 : (t > 4294967295.0 ? 4294967295.0 : t);
    return (unsigned int)t;   // monotone non-decreasing in key
}

// ---------------- fused: count_rank (blocks [0,CNT)) || proj (blocks [CNT, CNT+PROJ)) ------
// count: atomic return IS the within-edge rank (device-scope atomic throughput-bound,
// ~16-18G/s — R9 proved padding can't help; this is the algorithmic floor).
// proj: p_abh[node][k] = half2(a_k, b_k); memory layout a0,b0,a1,b1,... (128B/node row).
__global__ void proj_count_kernel(const float* __restrict__ x, const float* __restrict__ W1,
                                  __half2* __restrict__ p_abh,
                                  const int* __restrict__ E, unsigned int* __restrict__ edge_cnt,
                                  unsigned int* __restrict__ rank) {
    __shared__ float sW[128 * 32];
    __shared__ float sx[8][64];
    if (blockIdx.x < CNT_BLOCKS) {
        unsigned int base = blockIdx.x * 2048 + threadIdx.x;
        int ev[8];
        unsigned int rr[8];
        #pragma unroll
        for (int c = 0; c < 8; ++c) {
            unsigned int j = base + 256u * c;
            if (j < NNZ) ev[c] = E[j];
        }
        #pragma unroll
        for (int c = 0; c < 8; ++c) {
            unsigned int j = base + 256u * c;
            if (j < NNZ) rr[c] = atomicAdd(&edge_cnt[ev[c]], 1u);
        }
        #pragma unroll
        for (int c = 0; c < 8; ++c) {
            unsigned int j = base + 256u * c;
            if (j < NNZ) rank[j] = rr[c];   // coalesced
        }
        return;
    }
    int pb = blockIdx.x - CNT_BLOCKS;
    for (int t = threadIdx.x; t < 128 * 32; t += 256) sW[t] = W1[t];
    int ln = threadIdx.x >> 5;
    int k  = threadIdx.x & 31;
    for (int g = 0; g < 8; ++g) {
        int base = pb * 64 + g * 8;
        __syncthreads();   // sW ready (g=0); sx safe to overwrite (g>0)
        for (int t = threadIdx.x; t < 512; t += 256) {
            int n = t >> 6, d = t & 63;
            int gn = base + n;
            sx[n][d] = (gn < N_NODES) ? x[(size_t)gn * 64 + d] : 0.f;
        }
        __syncthreads();
        int node = base + ln;
        if (node < N_NODES) {
            float sa = 0.f, sb = 0.f;
            for (int d = 0; d < 64; ++d) {
                float xv = sx[ln][d];
                sa += xv * sW[d * 32 + k];
                sb += xv * sW[(64 + d) * 32 + k];
            }
            p_abh[(size_t)node * 32 + k] = __floats2half2_rn(sa, sb);   // coalesced 4B/lane
        }
    }
}

__global__ void scanA_kernel(const unsigned int* __restrict__ edge_cnt,
                             unsigned int* __restrict__ edge_off, unsigned int* __restrict__ bsums) {
    __shared__ unsigned int s[256];
    int tid = threadIdx.x;
    int base = blockIdx.x * 1024 + tid * 4;
    unsigned int v0 = (base + 0 < N_EDGES) ? edge_cnt[base + 0] : 0u;
    unsigned int v1 = (base + 1 < N_EDGES) ? edge_cnt[base + 1] : 0u;
    unsigned int v2 = (base + 2 < N_EDGES) ? edge_cnt[base + 2] : 0u;
    unsigned int v3 = (base + 3 < N_EDGES) ? edge_cnt[base + 3] : 0u;
    unsigned int tsum = v0 + v1 + v2 + v3;
    s[tid] = tsum;
    __syncthreads();
    for (int off = 1; off < 256; off <<= 1) {
        unsigned int t = (tid >= off) ? s[tid - off] : 0u;
        __syncthreads();
        s[tid] += t;
        __syncthreads();
    }
    unsigned int excl = s[tid] - tsum;
    if (base + 0 < N_EDGES) edge_off[base + 0] = excl;
    if (base + 1 < N_EDGES) edge_off[base + 1] = excl + v0;
    if (base + 2 < N_EDGES) edge_off[base + 2] = excl + v0 + v1;
    if (base + 3 < N_EDGES) edge_off[base + 3] = excl + v0 + v1 + v2;
    if (tid == 255) bsums[blockIdx.x] = s[255];
}

// scanB inlined: each block needs only the exclusive sum of bsums[0 .. blockIdx>>2).
// block 0 thread 0 writes the sentinel edge_off[N_EDGES] = NNZ (deg via diff everywhere).
__global__ void scanC_kernel(unsigned int* __restrict__ edge_off, const unsigned int* __restrict__ bsums) {
    __shared__ unsigned int sred[4];
    unsigned int need = blockIdx.x >> 2;       // <= 195 < 256
    unsigned int v = (threadIdx.x < need) ? bsums[threadIdx.x] : 0u;
    #pragma unroll
    for (int o = 32; o > 0; o >>= 1) v += __shfl_down(v, o);
    if ((threadIdx.x & 63) == 0) sred[threadIdx.x >> 6] = v;
    __syncthreads();
    unsigned int base = sred[0] + sred[1] + sred[2] + sred[3];
    int i = blockIdx.x * 256 + threadIdx.x;
    if (i < N_EDGES) edge_off[i] += base;
    if (blockIdx.x == 0 && threadIdx.x == 0) edge_off[N_EDGES] = NNZ;   // sentinel
}

// XCD-local CSR scatter (see R3): pass p = blockIdx&7 handles a ~2MB vj region per XCD L2.
__global__ void scatter_kernel(const int* __restrict__ V, const int* __restrict__ E,
                               const unsigned int* __restrict__ edge_off,
                               const unsigned int* __restrict__ rank,
                               uint2* __restrict__ vj) {
    unsigned int pass = blockIdx.x & 7u;
    unsigned int q    = blockIdx.x >> 3;
    unsigned int elo  = pass * SC_EPP;
    const unsigned int stride = (SC_BLOCKS / 8) * 256;
    for (unsigned int j = q * 256u + threadIdx.x; j < NNZ; j += stride) {
        unsigned int e = (unsigned int)__builtin_nontemporal_load(E + j);
        if (e - elo < (unsigned int)SC_EPP) {
            unsigned int pp = edge_off[e] + __builtin_nontemporal_load(rank + j);
            unsigned int v  = (unsigned int)__builtin_nontemporal_load(V + j);
            vj[pp] = make_uint2(v, j);
        }
    }
}

// ---------------- fused per-edge mean + per-incidence MLP (R5 structure, fp16 table) -------
// Wave = 4 groups x 16 lanes, ONE edge per wave. Lane l loads uint2 = 2 half2 = (a_2l, b_2l,
// a_2l+1, b_2l+1) — 128B/member gather (was 256B f32). All arithmetic stays f32.
__global__ void edge_logit_kernel(const uint2* __restrict__ vj,
                                  const unsigned int* __restrict__ edge_off,
                                  const uint2* __restrict__ pab,   // __half2 pairs
                                  const float* __restrict__ b1, const float* __restrict__ W2,
                                  const float* __restrict__ b2,
                                  float* __restrict__ probs_b, float* __restrict__ o_ep) {
    __shared__ float slog[4][32];        // per-incidence logits
    __shared__ unsigned int sv[4][32];   // per-wave member-id broadcast (exec-mask-safe)
    int e = blockIdx.x * 4 + (threadIdx.x >> 6);
    if (e >= N_EDGES) return;
    int w    = threadIdx.x >> 6;
    int lane = threadIdx.x & 63;
    int g    = lane >> 4;                // member-slot group 0..3
    int l    = lane & 15;                // k-pair index: k = 2l, 2l+1

    unsigned int off = edge_off[e];
    unsigned int deg = edge_off[e + 1] - off;
    unsigned int mind = deg < 32u ? deg : 32u;

    if ((unsigned int)lane < mind) sv[w][lane] = vj[off + lane].x;

    float2 w2  = ((const float2*)W2)[l];
    float2 bb1 = ((const float2*)b1)[l];
    float  b2v = b2[0];

    float2 aA[8];
    float2 bacc = make_float2(0.f, 0.f);
    #pragma unroll 8
    for (unsigned int m = 0; m < 8u; ++m) {
        if (4u * m >= mind) break;               // wave-uniform exit
        unsigned int idx = 4u * m + (unsigned int)g;
        if (idx < mind) {
            unsigned int v = sv[w][idx];
            uint2 r = pab[(size_t)v * 16u + l];
            float2 f0 = __half22float2(*reinterpret_cast<__half2*>(&r.x));  // (a_2l,  b_2l)
            float2 f1 = __half22float2(*reinterpret_cast<__half2*>(&r.y));  // (a_2l+1,b_2l+1)
            aA[m] = make_float2(f0.x, f1.x);
            bacc.x += f0.y;
            bacc.y += f1.y;
        } else {
            aA[m] = make_float2(0.f, 0.f);
        }
    }
    for (unsigned int ii = 32u + (unsigned int)g; ii < deg; ii += 4u) {   // deg>32 tail: b only
        unsigned int v = vj[off + ii].x;
        uint2 r = pab[(size_t)v * 16u + l];
        float2 f0 = __half22float2(*reinterpret_cast<__half2*>(&r.x));
        float2 f1 = __half22float2(*reinterpret_cast<__half2*>(&r.y));
        bacc.x += f0.y;
        bacc.y += f1.y;
    }
    bacc.x += __shfl_xor(bacc.x, 16);
    bacc.y += __shfl_xor(bacc.y, 16);
    bacc.x += __shfl_xor(bacc.x, 32);
    bacc.y += __shfl_xor(bacc.y, 32);
    float cc = (float)(deg > 1u ? deg : 1u);
    float2 em2 = make_float2(bacc.x / cc + bb1.x, bacc.y / cc + bb1.y);

    #pragma unroll 8
    for (unsigned int m = 0; m < 8u; ++m) {
        if (4u * m >= mind) break;               // wave-uniform exit
        unsigned int idx = 4u * m + (unsigned int)g;
        float h0 = aA[m].x + em2.x;
        float h1 = aA[m].y + em2.y;
        h0 = h0 > 0.f ? h0 : 0.f;
        h1 = h1 > 0.f ? h1 : 0.f;
        float t = h0 * w2.x + h1 * w2.y;
        #pragma unroll
        for (int o = 8; o > 0; o >>= 1) t += __shfl_down(t, o, 16);
        if (l == 0 && idx < mind) slog[w][idx] = t;
    }
    float prsum = 0.f;
    if ((unsigned int)lane < mind) {
        float pr = 1.f / (1.f + __expf(-(slog[w][lane] + b2v)));
        probs_b[off + lane] = pr;      // coalesced
        prsum = pr;
    }
    for (unsigned int ii = 32u + (unsigned int)g; ii < deg; ii += 4u) {   // deg>32 tail
        unsigned int v = vj[off + ii].x;
        uint2 r = pab[(size_t)v * 16u + l];
        float2 f0 = __half22float2(*reinterpret_cast<__half2*>(&r.x));
        float2 f1 = __half22float2(*reinterpret_cast<__half2*>(&r.y));
        float h0 = f0.x + em2.x;
        float h1 = f1.x + em2.y;
        h0 = h0 > 0.f ? h0 : 0.f;
        h1 = h1 > 0.f ? h1 : 0.f;
        float t = h0 * w2.x + h1 * w2.y;
        #pragma unroll
        for (int o = 8; o > 0; o >>= 1) t += __shfl_down(t, o, 16);
        if (l == 0) {
            float pr = 1.f / (1.f + __expf(-(t + b2v)));
            probs_b[off + ii] = pr;
            prsum += pr;
        }
    }
    #pragma unroll
    for (int o = 32; o > 0; o >>= 1) prsum += __shfl_down(prsum, o, 64);
    if (lane == 0) o_ep[e] = prsum / cc;
}

// ---------------- radix-scan helper (inlined redundantly per block) ----------------
__device__ __forceinline__ void radix_sel_256(const unsigned int* __restrict__ h,
                                              unsigned int target,
                                              unsigned int* csum, unsigned int* sres,
                                              unsigned int& out_bin, unsigned int& out_rem) {
    int t = threadIdx.x;
    unsigned int b[8];
    unsigned int s = 0;
    #pragma unroll
    for (int i = 0; i < 8; ++i) { b[i] = h[t * 8 + i]; s += b[i]; }
    csum[t] = s;
    __syncthreads();
    for (int off = 1; off < 256; off <<= 1) {
        unsigned int v = (t + off < 256) ? csum[t + off] : 0u;
        __syncthreads();
        csum[t] += v;
        __syncthreads();
    }
    unsigned int above = csum[t] - s;       // sum over chunks > t
    if (above < target && target <= above + s) {
        unsigned int rem = target - above;
        unsigned int cum = 0;
        #pragma unroll
        for (int i = 7; i >= 0; --i) {
            if (rem <= cum + b[i]) {
                sres[0] = (unsigned int)(t * 8 + i);
                sres[1] = rem - cum;
                break;
            }
            cum += b[i];
        }
    }
    __syncthreads();
    out_bin = sres[0];
    out_rem = sres[1];
    __syncthreads();
}

// ---------------- 2-level radix histogram on f32 keys ----------------
__global__ void hist1_kernel(const float* __restrict__ probs_b, unsigned int* __restrict__ hist) {
    __shared__ unsigned int lh[4][2048 + 8];
    for (int t = threadIdx.x; t < 4 * (2048 + 8); t += 256) ((unsigned int*)lh)[t] = 0;
    __syncthreads();
    int sub = threadIdx.x & 3;
    const float4* p4 = (const float4*)probs_b;
    for (unsigned int i = blockIdx.x * 256 + threadIdx.x; i < NNZ / 4; i += gridDim.x * 256) {
        float4 v = p4[i];
        atomicAdd(&lh[sub][__float_as_uint(v.x) >> 21], 1u);
        atomicAdd(&lh[sub][__float_as_uint(v.y) >> 21], 1u);
        atomicAdd(&lh[sub][__float_as_uint(v.z) >> 21], 1u);
        atomicAdd(&lh[sub][__float_as_uint(v.w) >> 21], 1u);
    }
    __syncthreads();
    for (int t = threadIdx.x; t < 2048; t += 256) {
        unsigned int s = lh[0][t] + lh[1][t] + lh[2][t] + lh[3][t];
        if (s) atomicAdd(&hist[t], s);
    }
}

// level-1 selection inlined; float4 loads.
__global__ void hist2_kernel(const float* __restrict__ probs_b,
                             const unsigned int* __restrict__ hist_ro,
                             unsigned int* __restrict__ hist) {
    __shared__ unsigned int csum[256];
    __shared__ unsigned int sres[2];
    __shared__ unsigned int lh[2048];
    unsigned int B1, rem_unused;
    radix_sel_256(hist_ro, (unsigned int)K_KEEP, csum, sres, B1, rem_unused);
    for (int t = threadIdx.x; t < 2048; t += 256) lh[t] = 0;
    __syncthreads();
    const float4* p4 = (const float4*)probs_b;
    for (unsigned int i = blockIdx.x * 256 + threadIdx.x; i < NNZ / 4; i += gridDim.x * 256) {
        float4 v = p4[i];
        unsigned int kx = __float_as_uint(v.x), ky = __float_as_uint(v.y);
        unsigned int kz = __float_as_uint(v.z), kw = __float_as_uint(v.w);
        if ((kx >> 21) == B1) atomicAdd(&lh[(kx >> 10) & 2047u], 1u);
        if ((ky >> 21) == B1) atomicAdd(&lh[(ky >> 10) & 2047u], 1u);
        if ((kz >> 21) == B1) atomicAdd(&lh[(kz >> 10) & 2047u], 1u);
        if ((kw >> 21) == B1) atomicAdd(&lh[(kw >> 10) & 2047u], 1u);
    }
    __syncthreads();
    for (int t = threadIdx.x; t < 2048; t += 256)
        if (lh[t]) atomicAdd(&hist[2048 + t], lh[t]);
}

// single-pass bandsel; level-2 selection inlined; lo/hi persisted (identical-value writes).
__global__ void bandsel_kernel(const float* __restrict__ probs_b, const int* __restrict__ E,
                               const uint2* __restrict__ vj,
                               const unsigned int* __restrict__ hist,
                               SelState* __restrict__ st,
                               unsigned int* __restrict__ band_p, unsigned int* __restrict__ band_j,
                               unsigned int* __restrict__ band_e, unsigned int* __restrict__ band_v) {
    __shared__ unsigned int csum[256];
    __shared__ unsigned int sres[2];
    __shared__ unsigned int whi[4];
    unsigned int B1, rem1, bin2, rem2_unused;
    radix_sel_256(hist, (unsigned int)K_KEEP, csum, sres, B1, rem1);
    radix_sel_256(hist + 2048, rem1, csum, sres, bin2, rem2_unused);
    unsigned int P = (B1 << 21) | (bin2 << 10);
    float lo = __uint_as_float(P) - DELTA;
    float hi = __uint_as_float(P + 1024u) + DELTA;
    if (threadIdx.x == 0) { st->lo_edge = lo; st->hi_edge = hi; }
    unsigned int nhi = 0;
    for (unsigned int p = blockIdx.x * 256 + threadIdx.x; p < NNZ; p += gridDim.x * 256) {
        float pk = probs_b[p];
        if (pk > hi) nhi++;
        else if (pk >= lo) {
            unsigned int s = atomicAdd(&st->band_n, 1u);
            if (s < BANDCAP) {
                uint2 t = vj[p];
                band_p[s] = p;
                band_j[s] = t.y;
                band_e[s] = (unsigned int)E[t.y];
                band_v[s] = t.x;
            }
        }
    }
    #pragma unroll
    for (int o = 32; o > 0; o >>= 1) nhi += __shfl_down(nhi, o);
    if ((threadIdx.x & 63) == 0) whi[threadIdx.x >> 6] = nhi;
    __syncthreads();
    if (threadIdx.x == 0) {
        unsigned int th = whi[0] + whi[1] + whi[2] + whi[3];
        if (th) atomicAdd(&st->n_hi, th);
    }
}

// exact f64 recompute for band members from x/W1 (fp16-independent — the safety net);
// W1 staged in LDS; bhist1 inlined (lane k==0 bins its freshly computed key).
__global__ void rescue_kernel(const uint2* __restrict__ vj,
                              const unsigned int* __restrict__ edge_off,
                              const float* __restrict__ x, const float* __restrict__ W1,
                              const float* __restrict__ b1, const float* __restrict__ W2,
                              const float* __restrict__ b2,
                              const unsigned int* __restrict__ band_e,
                              const unsigned int* __restrict__ band_v,
                              const SelState* __restrict__ st,
                              unsigned long long* __restrict__ band_key,
                              unsigned int* __restrict__ hist) {
    unsigned int n = st->band_n; if (n > BANDCAP) n = BANDCAP;
    if (blockIdx.x * 8 >= n) return;
    __shared__ float sW[128 * 32];
    for (int t = threadIdx.x; t < 128 * 32; t += 256) sW[t] = W1[t];
    __syncthreads();
    unsigned int g = blockIdx.x * 8 + (threadIdx.x >> 5);
    if (g >= n) return;
    int k = threadIdx.x & 31;
    unsigned int v = band_v[g];
    unsigned int e = band_e[g];
    unsigned int off = edge_off[e];
    unsigned int deg = edge_off[e + 1] - off;

    const float* xv = x + (size_t)v * 64u;
    double a = 0.0;
    #pragma unroll 8
    for (int d = 0; d < 64; ++d) a += (double)xv[d] * (double)sW[d * 32 + k];
    double bsum = 0.0;
    for (unsigned int m = off; m < off + deg; ++m) {
        const float* xm = x + (size_t)vj[m].x * 64u;
        double acc = 0.0;
        #pragma unroll 8
        for (int d = 0; d < 64; ++d) acc += (double)xm[d] * (double)sW[(64 + d) * 32 + k];
        bsum += acc;
    }
    double cc = (double)(deg > 1u ? deg : 1u);
    double h = a + bsum / cc + (double)b1[k];
    h = h > 0.0 ? h : 0.0;
    double t = h * (double)W2[k];
    #pragma unroll
    for (int o = 16; o > 0; o >>= 1) t += __shfl_down(t, o, 32);
    if (k == 0) {
        double pr = 1.0 / (1.0 + exp(-(t + (double)b2[0])));
        band_key[g] = (unsigned long long)__double_as_longlong(pr);
        unsigned int u = band_u32(pr, st->lo_edge);
        atomicAdd(&hist[4096 + (u >> 21)], 1u);   // inlined bhist1
    }
}

// band level-1 selection inlined.
__global__ void bhist2_kernel(const unsigned long long* __restrict__ band_key,
                              const SelState* __restrict__ st, unsigned int* __restrict__ hist) {
    __shared__ unsigned int csum[256];
    __shared__ unsigned int sres[2];
    __shared__ unsigned int lh[2048];
    unsigned int bB1, rem_unused;
    radix_sel_256(hist + 4096, (unsigned int)K_KEEP - st->n_hi, csum, sres, bB1, rem_unused);
    for (int t = threadIdx.x; t < 2048; t += 256) lh[t] = 0;
    __syncthreads();
    unsigned int n = st->band_n; if (n > BANDCAP) n = BANDCAP;
    float lo = st->lo_edge;
    for (unsigned int i = blockIdx.x * 256 + threadIdx.x; i < n; i += gridDim.x * 256) {
        unsigned int u = band_u32(__longlong_as_double((long long)band_key[i]), lo);
        if ((u >> 21) == bB1) atomicAdd(&lh[(u >> 10) & 2047u], 1u);
    }
    __syncthreads();
    for (int t = threadIdx.x; t < 2048; t += 256)
        if (lh[t]) atomicAdd(&hist[6144 + t], lh[t]);
}

// both band scans inlined; block 0 persists bU0/brem2 for btierank; blocks beyond band_n
// early-exit before the radix preambles.
__global__ void btie_kernel(const unsigned long long* __restrict__ band_key,
                            const unsigned int* __restrict__ band_j,
                            const unsigned int* __restrict__ band_p,
                            const unsigned int* __restrict__ hist,
                            SelState* __restrict__ st, unsigned char* __restrict__ flag,
                            unsigned long long* __restrict__ tie_k,
                            unsigned int* __restrict__ tie_j, unsigned int* __restrict__ tie_p) {
    unsigned int n = st->band_n; if (n > BANDCAP) n = BANDCAP;
    if (blockIdx.x != 0 && blockIdx.x * 256u >= n) return;   // uniform early-exit
    __shared__ unsigned int csum[256];
    __shared__ unsigned int sres[2];
    unsigned int bB1, brem1, bin2, brem2;
    radix_sel_256(hist + 4096, (unsigned int)K_KEEP - st->n_hi, csum, sres, bB1, brem1);
    radix_sel_256(hist + 6144, brem1, csum, sres, bin2, brem2);
    unsigned int U0 = (bB1 << 21) | (bin2 << 10);
    if (blockIdx.x == 0 && threadIdx.x == 0) { st->bU0 = U0; st->brem2 = brem2; }
    unsigned int i = blockIdx.x * 256 + threadIdx.x;
    if (i >= n) return;
    float lo = st->lo_edge;
    unsigned long long key = band_key[i];
    unsigned int u = band_u32(__longlong_as_double((long long)key), lo);
    if (u >= U0 + 1024u) {
        flag[band_p[i]] = 2u;
    } else if (u >= U0) {
        unsigned int s = atomicAdd(&st->tie_n, 1u);
        if (s < TIECAP) { tie_k[s] = key; tie_j[s] = band_j[i]; tie_p[s] = band_p[i]; }
    }
}

// exact rank inside the (tiny) tie bucket by (key desc, j asc); take first brem2
__global__ void btierank_kernel(const unsigned long long* __restrict__ tie_k,
                                const unsigned int* __restrict__ tie_j,
                                const unsigned int* __restrict__ tie_p,
                                const SelState* __restrict__ st, unsigned char* __restrict__ flag) {
    unsigned int n = st->tie_n; if (n > TIECAP) n = TIECAP;
    unsigned int need = st->brem2;
    for (unsigned int i = threadIdx.x; i < n; i += 256) {
        unsigned long long ki = tie_k[i];
        unsigned int ji = tie_j[i];
        unsigned int r = 0;
        for (unsigned int q = 0; q < n; ++q) {
            unsigned long long kq = tie_k[q];
            if (kq > ki || (kq == ki && tie_j[q] < ji)) r++;
        }
        if (r < need) flag[tie_p[i]] = 2u;
    }
}

// fused outputs: blocks [0,OUT) j-order incidence outputs (4 j's/thread, float4);
// blocks [OUT, OUT+EOUT) per-edge outputs.
__global__ void outs_kernel(const float* __restrict__ probs_b, const unsigned char* __restrict__ flag,
                            const int* __restrict__ E, const unsigned int* __restrict__ rank,
                            const unsigned int* __restrict__ edge_off,
                            const SelState* __restrict__ st,
                            float* __restrict__ o_probs, float* __restrict__ o_soft,
                            float* __restrict__ o_hard,
                            float* __restrict__ o_es, float* __restrict__ o_eh) {
    float hi = st->hi_edge;
    if (blockIdx.x < OUT_BLOCKS) {
        unsigned int j0 = (blockIdx.x * 256 + threadIdx.x) * 4u;
        if (j0 >= NNZ) return;   // NNZ % 4 == 0
        int4  e4 = *reinterpret_cast<const int4*>(E + j0);
        uint4 r4 = *reinterpret_cast<const uint4*>(rank + j0);
        unsigned int p0 = edge_off[e4.x] + r4.x;
        unsigned int p1 = edge_off[e4.y] + r4.y;
        unsigned int p2 = edge_off[e4.z] + r4.z;
        unsigned int p3 = edge_off[e4.w] + r4.w;
        float pk0 = probs_b[p0], pk1 = probs_b[p1], pk2 = probs_b[p2], pk3 = probs_b[p3];
        unsigned char f0 = flag[p0], f1 = flag[p1], f2 = flag[p2], f3 = flag[p3];
        float4 pr = make_float4(pk0, pk1, pk2, pk3);
        float4 hb = make_float4((pk0 > hi || f0 == 2u) ? 1.f : 0.f,
                                (pk1 > hi || f1 == 2u) ? 1.f : 0.f,
                                (pk2 > hi || f2 == 2u) ? 1.f : 0.f,
                                (pk3 > hi || f3 == 2u) ? 1.f : 0.f);
        *reinterpret_cast<float4*>(o_probs + j0) = pr;
        *reinterpret_cast<float4*>(o_soft  + j0) = hb;
        *reinterpret_cast<float4*>(o_hard  + j0) = hb;
    } else {
        unsigned int e = (blockIdx.x - OUT_BLOCKS) * 256 + threadIdx.x;
        if (e >= N_EDGES) return;
        unsigned int off = edge_off[e];
        unsigned int deg = edge_off[e + 1] - off;
        unsigned int cnt = 0;
        for (unsigned int i = 0; i < deg; ++i)
            cnt += (probs_b[off + i] > hi || flag[off + i] == 2u) ? 1u : 0u;
        float cc = (float)(deg > 1u ? deg : 1u);
        o_es[e] = (float)cnt / cc;
        o_eh[e] = cnt ? 1.f : 0.f;
    }
}

extern "C" void kernel_launch(void* const* d_in, const int* in_sizes, int n_in,
                              void* d_out, int out_size, void* d_ws, size_t ws_size,
                              hipStream_t stream) {
    const float* x  = (const float*)d_in[0];
    const int*   V  = (const int*)d_in[1];
    const int*   E  = (const int*)d_in[2];
    const float* W1 = (const float*)d_in[3];
    const float* b1 = (const float*)d_in[4];
    const float* W2 = (const float*)d_in[5];
    const float* b2 = (const float*)d_in[6];

    float* out     = (float*)d_out;
    float* o_probs = out;
    float* o_soft  = out + NNZ;
    float* o_hard  = out + 2 * (size_t)NNZ;
    float* o_ep    = out + 3 * (size_t)NNZ;
    float* o_es    = out + 3 * (size_t)NNZ + N_EDGES;
    float* o_eh    = out + 3 * (size_t)NNZ + 2 * (size_t)N_EDGES;

    char* w = (char*)d_ws;
    __half2*            p_abh    = (__half2*)(w + OFF_PAB);
    float*              probs_b  = (float*)(w + OFF_PB32);
    uint2*              vj       = (uint2*)(w + OFF_VJ);
    unsigned int*       rank     = (unsigned int*)(w + OFF_RANK);
    unsigned int*       edge_off = (unsigned int*)(w + OFF_EOFF);
    unsigned int*       bsums    = (unsigned int*)(w + OFF_BS);
    unsigned int*       band_p   = (unsigned int*)(w + OFF_BANDP);
    unsigned int*       band_j   = (unsigned int*)(w + OFF_BANDJ);
    unsigned int*       band_e   = (unsigned int*)(w + OFF_BANDE);
    unsigned int*       band_v   = (unsigned int*)(w + OFF_BANDV);
    unsigned long long* band_key = (unsigned long long*)(w + OFF_BANDK);
    unsigned long long* tie_k    = (unsigned long long*)(w + OFF_TIEK);
    unsigned int*       tie_j    = (unsigned int*)(w + OFF_TIEJ);
    unsigned int*       tie_p    = (unsigned int*)(w + OFF_TIEP);
    unsigned char*      flag     = (unsigned char*)(w + OFF_FLAG);
    unsigned int*       edge_cnt = (unsigned int*)(w + OFF_ECNT);
    unsigned int*       hist     = (unsigned int*)(w + OFF_HIST);
    SelState*           st       = (SelState*)(w + OFF_ST);

    hipMemsetAsync(w + ZERO_OFF, 0, ZERO_LEN, stream);

    proj_count_kernel<<<CNT_BLOCKS + PROJ_BLOCKS, 256, 0, stream>>>(x, W1, p_abh, E, edge_cnt, rank);
    scanA_kernel<<<SCAN_BLOCKS, 256, 0, stream>>>(edge_cnt, edge_off, bsums);
    scanC_kernel<<<(N_EDGES + 255) / 256, 256, 0, stream>>>(edge_off, bsums);
    scatter_kernel<<<SC_BLOCKS, 256, 0, stream>>>(V, E, edge_off, rank, vj);

    edge_logit_kernel<<<(N_EDGES + 3) / 4, 256, 0, stream>>>(vj, edge_off,
                                                             (const uint2*)p_abh,
                                                             b1, W2, b2, probs_b, o_ep);

    hist1_kernel<<<1024, 256, 0, stream>>>(probs_b, hist);
    hist2_kernel<<<1024, 256, 0, stream>>>(probs_b, hist, hist);
    bandsel_kernel<<<1024, 256, 0, stream>>>(probs_b, E, vj, hist, st,
                                             band_p, band_j, band_e, band_v);
    rescue_kernel<<<BANDCAP / 8, 256, 0, stream>>>(vj, edge_off, x, W1, b1, W2, b2,
                                                   band_e, band_v, st, band_key, hist);

    bhist2_kernel<<<64, 256, 0, stream>>>(band_key, st, hist);
    btie_kernel<<<BANDCAP / 256, 256, 0, stream>>>(band_key, band_j, band_p, hist, st, flag,
                                                   tie_k, tie_j, tie_p);
    btierank_kernel<<<1, 256, 0, stream>>>(tie_k, tie_j, tie_p, st, flag);

    outs_kernel<<<OUT_BLOCKS + EOUT_BLOCKS, 256, 0, stream>>>(probs_b, flag, E, rank, edge_off,
                                                              st, o_probs, o_soft, o_hard,
                                                              o_es, o_eh);
}

// Round 11
// 558.869 us; speedup vs baseline: 1.5594x; 1.5594x over previous
//
#include <hip/hip_runtime.h>
#include <math.h>

#define N_NODES   100000
#define N_EDGES   200000
#define NNZ       2000000
#define K_KEEP    1000000
#define BANDCAP   131072
#define TIECAP    4096
// DELTA bounds |p_f32 - p_f64|: f32 pipeline error <= ~3e-6 (64-term dots + mean + W2 dot,
// sigmoid slope 0.25). 1e-4 keeps >30x margin; rescue cost linear in band width.
// R10 ERRATUM: fp16 table forced DELTA=2e-3 -> band_n ~40k -> bandsel same-address atomics
// (242us) + rescue f64 (~200us) exploded. DELTA is the master coupling constant: any change
// re-prices bandsel/rescue/btie. Reverted to f32 table + 1e-4.
#define DELTA     1.0e-4f
#define SCAN_BLOCKS 196   // ceil(200000/1024)
#define USCALE (4294967296.0 / 4.0e-3)   // band key -> u32 map; band width < 4e-3 guaranteed

#define SC_PASSES 8
#define SC_EPP    (N_EDGES / SC_PASSES)   // 25000 edges per pass (~2MB vj region, fits XCD L2)
#define SC_BLOCKS 2048                    // 256 blocks per pass

// fused-dispatch grid splits
#define CNT_BLOCKS  ((NNZ + 2047) / 2048)        // 977  count_rank blocks (first: critical path)
#define PROJ_BLOCKS ((N_NODES + 63) / 64)        // 1563 proj blocks (64 nodes each)
#define OUT_BLOCKS  ((NNZ / 4 + 255) / 256)      // 1954
#define EOUT_BLOCKS ((N_EDGES + 255) / 256)      // 782

// ---------------- workspace layout (bytes) ----------------
#define OFF_PAB   ((size_t)0)          // float2 p_ab2 [N_NODES*32] 25,600,000 (.x=a_vk, .y=b_vk)
#define OFF_PB32  ((size_t)25600000)   // f32 probs_b [NNZ]        8,000,000 (CSR/p-order probs)
#define OFF_VJ    ((size_t)33600000)   // uint2 vj [NNZ]          16,000,000 (.x=vertex, .y=orig j)
#define OFF_RANK  ((size_t)49600000)   // u32 rank [NNZ] j->rank-in-edge  8,000,000
#define OFF_EOFF  ((size_t)57600000)   // u32 edge_off [N_EDGES+1]   800,004 (sentinel spills
                                       // into the unused OFF_CUR slot)
#define OFF_CUR   ((size_t)58400000)   // (unused; first 4B = edge_off sentinel)
#define OFF_BS    ((size_t)59200000)   // u32 bsums [256]              1,024
#define OFF_BANDP ((size_t)59201024)   // u32 band_p [BANDCAP]       524,288
#define OFF_BANDJ ((size_t)59725312)   // u32 band_j [BANDCAP]       524,288
#define OFF_BANDE ((size_t)60249600)   // u32 band_e [BANDCAP]       524,288
#define OFF_BANDV ((size_t)60773888)   // u32 band_v [BANDCAP]       524,288
#define OFF_BANDK ((size_t)61298176)   // u64 band_key [BANDCAP]   1,048,576
#define OFF_TIEK  ((size_t)62346752)   // u64 tie_k [TIECAP]          32,768
#define OFF_TIEJ  ((size_t)62379520)   // u32 tie_j [TIECAP]          16,384
#define OFF_TIEP  ((size_t)62395904)   // u32 tie_p [TIECAP]          16,384
// --- zero region ---
#define OFF_FLAG  ((size_t)62412288)   // u8  flag [NNZ]           2,000,000 (0 none, 2 selected)
#define OFF_ECNT  ((size_t)64412288)   // u32 edge_cnt [N_EDGES]     800,000 (zeroed by memset)
#define OFF_HIST  ((size_t)65212288)   // u32 hist [4*2048]           32,768
#define OFF_ST    ((size_t)65245056)   // SelState (padded)              256
#define ZERO_OFF  OFF_FLAG
#define ZERO_LEN  ((size_t)(65245312 - 62412288))

// hot atomic counters (n_hi, band_n, tie_n) each on their own 64B line
struct SelState {
    unsigned int B1;        // (unused)
    unsigned int rem1;      // (unused)
    float lo_edge, hi_edge; // band boundaries (written redundantly by bandsel blocks)
    unsigned int bB1;       // (unused)
    unsigned int brem1;     // (unused)
    unsigned int bU0;       // threshold u-bucket base (written by btie block 0)
    unsigned int brem2;     // remaining rank within the u-bucket (written by btie block 0)
    unsigned int _pad0[8];  // -> 64 B
    unsigned int n_hi;      unsigned int _pad1[15];   // own line
    unsigned int band_n;    unsigned int _pad2[15];   // own line
    unsigned int tie_n;     unsigned int _pad3[15];   // own line
};

__device__ __forceinline__ unsigned int band_u32(double key, float lo) {
    double t = (key - (double)lo) * USCALE;
    t = t < 0.0 ? 0.0 : (t > 4294967295.0 ? 4294967295.0 : t);
    return (unsigned int)t;   // monotone non-decreasing in key
}

// ---------------- fused: count_rank (blocks [0,CNT)) || proj (blocks [CNT, CNT+PROJ)) ------
// count: atomic return IS the within-edge rank (device-scope atomic throughput-bound,
// ~16-18G/s — R9 proved padding can't help; this is the algorithmic floor).
// proj: stages W1 once per block, loops 8x8 nodes (W1 L2 traffic 200MB -> 25MB).
__global__ void proj_count_kernel(const float* __restrict__ x, const float* __restrict__ W1,
                                  float2* __restrict__ p_ab2,
                                  const int* __restrict__ E, unsigned int* __restrict__ edge_cnt,
                                  unsigned int* __restrict__ rank) {
    __shared__ float sW[128 * 32];
    __shared__ float sx[8][64];
    if (blockIdx.x < CNT_BLOCKS) {
        unsigned int base = blockIdx.x * 2048 + threadIdx.x;
        int ev[8];
        unsigned int rr[8];
        #pragma unroll
        for (int c = 0; c < 8; ++c) {
            unsigned int j = base + 256u * c;
            if (j < NNZ) ev[c] = E[j];
        }
        #pragma unroll
        for (int c = 0; c < 8; ++c) {
            unsigned int j = base + 256u * c;
            if (j < NNZ) rr[c] = atomicAdd(&edge_cnt[ev[c]], 1u);
        }
        #pragma unroll
        for (int c = 0; c < 8; ++c) {
            unsigned int j = base + 256u * c;
            if (j < NNZ) rank[j] = rr[c];   // coalesced
        }
        return;
    }
    int pb = blockIdx.x - CNT_BLOCKS;
    for (int t = threadIdx.x; t < 128 * 32; t += 256) sW[t] = W1[t];
    int ln = threadIdx.x >> 5;
    int k  = threadIdx.x & 31;
    for (int g = 0; g < 8; ++g) {
        int base = pb * 64 + g * 8;
        __syncthreads();   // sW ready (g=0); sx safe to overwrite (g>0)
        for (int t = threadIdx.x; t < 512; t += 256) {
            int n = t >> 6, d = t & 63;
            int gn = base + n;
            sx[n][d] = (gn < N_NODES) ? x[(size_t)gn * 64 + d] : 0.f;
        }
        __syncthreads();
        int node = base + ln;
        if (node < N_NODES) {
            float sa = 0.f, sb = 0.f;
            for (int d = 0; d < 64; ++d) {
                float xv = sx[ln][d];
                sa += xv * sW[d * 32 + k];
                sb += xv * sW[(64 + d) * 32 + k];
            }
            p_ab2[(size_t)node * 32 + k] = make_float2(sa, sb);
        }
    }
}

__global__ void scanA_kernel(const unsigned int* __restrict__ edge_cnt,
                             unsigned int* __restrict__ edge_off, unsigned int* __restrict__ bsums) {
    __shared__ unsigned int s[256];
    int tid = threadIdx.x;
    int base = blockIdx.x * 1024 + tid * 4;
    unsigned int v0 = (base + 0 < N_EDGES) ? edge_cnt[base + 0] : 0u;
    unsigned int v1 = (base + 1 < N_EDGES) ? edge_cnt[base + 1] : 0u;
    unsigned int v2 = (base + 2 < N_EDGES) ? edge_cnt[base + 2] : 0u;
    unsigned int v3 = (base + 3 < N_EDGES) ? edge_cnt[base + 3] : 0u;
    unsigned int tsum = v0 + v1 + v2 + v3;
    s[tid] = tsum;
    __syncthreads();
    for (int off = 1; off < 256; off <<= 1) {
        unsigned int t = (tid >= off) ? s[tid - off] : 0u;
        __syncthreads();
        s[tid] += t;
        __syncthreads();
    }
    unsigned int excl = s[tid] - tsum;
    if (base + 0 < N_EDGES) edge_off[base + 0] = excl;
    if (base + 1 < N_EDGES) edge_off[base + 1] = excl + v0;
    if (base + 2 < N_EDGES) edge_off[base + 2] = excl + v0 + v1;
    if (base + 3 < N_EDGES) edge_off[base + 3] = excl + v0 + v1 + v2;
    if (tid == 255) bsums[blockIdx.x] = s[255];
}

// scanB inlined: each block needs only the exclusive sum of bsums[0 .. blockIdx>>2).
// block 0 thread 0 writes the sentinel edge_off[N_EDGES] = NNZ (deg via diff everywhere).
__global__ void scanC_kernel(unsigned int* __restrict__ edge_off, const unsigned int* __restrict__ bsums) {
    __shared__ unsigned int sred[4];
    unsigned int need = blockIdx.x >> 2;       // <= 195 < 256
    unsigned int v = (threadIdx.x < need) ? bsums[threadIdx.x] : 0u;
    #pragma unroll
    for (int o = 32; o > 0; o >>= 1) v += __shfl_down(v, o);
    if ((threadIdx.x & 63) == 0) sred[threadIdx.x >> 6] = v;
    __syncthreads();
    unsigned int base = sred[0] + sred[1] + sred[2] + sred[3];
    int i = blockIdx.x * 256 + threadIdx.x;
    if (i < N_EDGES) edge_off[i] += base;
    if (blockIdx.x == 0 && threadIdx.x == 0) edge_off[N_EDGES] = NNZ;   // sentinel
}

// XCD-local CSR scatter (see R3): pass p = blockIdx&7 handles a ~2MB vj region per XCD L2.
__global__ void scatter_kernel(const int* __restrict__ V, const int* __restrict__ E,
                               const unsigned int* __restrict__ edge_off,
                               const unsigned int* __restrict__ rank,
                               uint2* __restrict__ vj) {
    unsigned int pass = blockIdx.x & 7u;
    unsigned int q    = blockIdx.x >> 3;
    unsigned int elo  = pass * SC_EPP;
    const unsigned int stride = (SC_BLOCKS / 8) * 256;
    for (unsigned int j = q * 256u + threadIdx.x; j < NNZ; j += stride) {
        unsigned int e = (unsigned int)__builtin_nontemporal_load(E + j);
        if (e - elo < (unsigned int)SC_EPP) {
            unsigned int pp = edge_off[e] + __builtin_nontemporal_load(rank + j);
            unsigned int v  = (unsigned int)__builtin_nontemporal_load(V + j);
            vj[pp] = make_uint2(v, j);
        }
    }
}

// ---------------- fused per-edge mean + per-incidence MLP (R5 structure) ----------
// Wave = 4 groups x 16 lanes, ONE edge per wave. deg = edge_off[e+1]-edge_off[e].
__global__ void edge_logit_kernel(const uint2* __restrict__ vj,
                                  const unsigned int* __restrict__ edge_off,
                                  const float2* __restrict__ p_ab2,
                                  const float* __restrict__ b1, const float* __restrict__ W2,
                                  const float* __restrict__ b2,
                                  float* __restrict__ probs_b, float* __restrict__ o_ep) {
    __shared__ float slog[4][32];        // per-incidence logits
    __shared__ unsigned int sv[4][32];   // per-wave member-id broadcast (exec-mask-safe)
    int e = blockIdx.x * 4 + (threadIdx.x >> 6);
    if (e >= N_EDGES) return;
    int w    = threadIdx.x >> 6;
    int lane = threadIdx.x & 63;
    int g    = lane >> 4;                // member-slot group 0..3
    int l    = lane & 15;                // k-pair index: k = 2l, 2l+1

    unsigned int off = edge_off[e];
    unsigned int deg = edge_off[e + 1] - off;
    unsigned int mind = deg < 32u ? deg : 32u;

    if ((unsigned int)lane < mind) sv[w][lane] = vj[off + lane].x;

    float2 w2  = ((const float2*)W2)[l];
    float2 bb1 = ((const float2*)b1)[l];
    float  b2v = b2[0];

    float2 aA[8];
    float2 bacc = make_float2(0.f, 0.f);
    #pragma unroll 8
    for (unsigned int m = 0; m < 8u; ++m) {
        if (4u * m >= mind) break;               // wave-uniform exit
        unsigned int idx = 4u * m + (unsigned int)g;
        if (idx < mind) {
            unsigned int v = sv[w][idx];
            float4 r = reinterpret_cast<const float4*>(p_ab2 + (size_t)v * 32u)[l];
            aA[m] = make_float2(r.x, r.z);
            bacc.x += r.y;
            bacc.y += r.w;
        } else {
            aA[m] = make_float2(0.f, 0.f);
        }
    }
    for (unsigned int ii = 32u + (unsigned int)g; ii < deg; ii += 4u) {   // deg>32 tail: b only
        unsigned int v = vj[off + ii].x;
        float4 r = reinterpret_cast<const float4*>(p_ab2 + (size_t)v * 32u)[l];
        bacc.x += r.y;
        bacc.y += r.w;
    }
    bacc.x += __shfl_xor(bacc.x, 16);
    bacc.y += __shfl_xor(bacc.y, 16);
    bacc.x += __shfl_xor(bacc.x, 32);
    bacc.y += __shfl_xor(bacc.y, 32);
    float cc = (float)(deg > 1u ? deg : 1u);
    float2 em2 = make_float2(bacc.x / cc + bb1.x, bacc.y / cc + bb1.y);

    #pragma unroll 8
    for (unsigned int m = 0; m < 8u; ++m) {
        if (4u * m >= mind) break;               // wave-uniform exit
        unsigned int idx = 4u * m + (unsigned int)g;
        float h0 = aA[m].x + em2.x;
        float h1 = aA[m].y + em2.y;
        h0 = h0 > 0.f ? h0 : 0.f;
        h1 = h1 > 0.f ? h1 : 0.f;
        float t = h0 * w2.x + h1 * w2.y;
        #pragma unroll
        for (int o = 8; o > 0; o >>= 1) t += __shfl_down(t, o, 16);
        if (l == 0 && idx < mind) slog[w][idx] = t;
    }
    float prsum = 0.f;
    if ((unsigned int)lane < mind) {
        float pr = 1.f / (1.f + __expf(-(slog[w][lane] + b2v)));
        probs_b[off + lane] = pr;      // coalesced
        prsum = pr;
    }
    for (unsigned int ii = 32u + (unsigned int)g; ii < deg; ii += 4u) {   // deg>32 tail
        unsigned int v = vj[off + ii].x;
        float4 r = reinterpret_cast<const float4*>(p_ab2 + (size_t)v * 32u)[l];
        float h0 = r.x + em2.x;
        float h1 = r.z + em2.y;
        h0 = h0 > 0.f ? h0 : 0.f;
        h1 = h1 > 0.f ? h1 : 0.f;
        float t = h0 * w2.x + h1 * w2.y;
        #pragma unroll
        for (int o = 8; o > 0; o >>= 1) t += __shfl_down(t, o, 16);
        if (l == 0) {
            float pr = 1.f / (1.f + __expf(-(t + b2v)));
            probs_b[off + ii] = pr;
            prsum += pr;
        }
    }
    #pragma unroll
    for (int o = 32; o > 0; o >>= 1) prsum += __shfl_down(prsum, o, 64);
    if (lane == 0) o_ep[e] = prsum / cc;
}

// ---------------- radix-scan helper (inlined redundantly per block) ----------------
__device__ __forceinline__ void radix_sel_256(const unsigned int* __restrict__ h,
                                              unsigned int target,
                                              unsigned int* csum, unsigned int* sres,
                                              unsigned int& out_bin, unsigned int& out_rem) {
    int t = threadIdx.x;
    unsigned int b[8];
    unsigned int s = 0;
    #pragma unroll
    for (int i = 0; i < 8; ++i) { b[i] = h[t * 8 + i]; s += b[i]; }
    csum[t] = s;
    __syncthreads();
    for (int off = 1; off < 256; off <<= 1) {
        unsigned int v = (t + off < 256) ? csum[t + off] : 0u;
        __syncthreads();
        csum[t] += v;
        __syncthreads();
    }
    unsigned int above = csum[t] - s;       // sum over chunks > t
    if (above < target && target <= above + s) {
        unsigned int rem = target - above;
        unsigned int cum = 0;
        #pragma unroll
        for (int i = 7; i >= 0; --i) {
            if (rem <= cum + b[i]) {
                sres[0] = (unsigned int)(t * 8 + i);
                sres[1] = rem - cum;
                break;
            }
            cum += b[i];
        }
    }
    __syncthreads();
    out_bin = sres[0];
    out_rem = sres[1];
    __syncthreads();
}

// ---------------- 2-level radix histogram on f32 keys ----------------
__global__ void hist1_kernel(const float* __restrict__ probs_b, unsigned int* __restrict__ hist) {
    __shared__ unsigned int lh[4][2048 + 8];
    for (int t = threadIdx.x; t < 4 * (2048 + 8); t += 256) ((unsigned int*)lh)[t] = 0;
    __syncthreads();
    int sub = threadIdx.x & 3;
    const float4* p4 = (const float4*)probs_b;
    for (unsigned int i = blockIdx.x * 256 + threadIdx.x; i < NNZ / 4; i += gridDim.x * 256) {
        float4 v = p4[i];
        atomicAdd(&lh[sub][__float_as_uint(v.x) >> 21], 1u);
        atomicAdd(&lh[sub][__float_as_uint(v.y) >> 21], 1u);
        atomicAdd(&lh[sub][__float_as_uint(v.z) >> 21], 1u);
        atomicAdd(&lh[sub][__float_as_uint(v.w) >> 21], 1u);
    }
    __syncthreads();
    for (int t = threadIdx.x; t < 2048; t += 256) {
        unsigned int s = lh[0][t] + lh[1][t] + lh[2][t] + lh[3][t];
        if (s) atomicAdd(&hist[t], s);
    }
}

// level-1 selection inlined; float4 loads.
__global__ void hist2_kernel(const float* __restrict__ probs_b,
                             const unsigned int* __restrict__ hist_ro,
                             unsigned int* __restrict__ hist) {
    __shared__ unsigned int csum[256];
    __shared__ unsigned int sres[2];
    __shared__ unsigned int lh[2048];
    unsigned int B1, rem_unused;
    radix_sel_256(hist_ro, (unsigned int)K_KEEP, csum, sres, B1, rem_unused);
    for (int t = threadIdx.x; t < 2048; t += 256) lh[t] = 0;
    __syncthreads();
    const float4* p4 = (const float4*)probs_b;
    for (unsigned int i = blockIdx.x * 256 + threadIdx.x; i < NNZ / 4; i += gridDim.x * 256) {
        float4 v = p4[i];
        unsigned int kx = __float_as_uint(v.x), ky = __float_as_uint(v.y);
        unsigned int kz = __float_as_uint(v.z), kw = __float_as_uint(v.w);
        if ((kx >> 21) == B1) atomicAdd(&lh[(kx >> 10) & 2047u], 1u);
        if ((ky >> 21) == B1) atomicAdd(&lh[(ky >> 10) & 2047u], 1u);
        if ((kz >> 21) == B1) atomicAdd(&lh[(kz >> 10) & 2047u], 1u);
        if ((kw >> 21) == B1) atomicAdd(&lh[(kw >> 10) & 2047u], 1u);
    }
    __syncthreads();
    for (int t = threadIdx.x; t < 2048; t += 256)
        if (lh[t]) atomicAdd(&hist[2048 + t], lh[t]);
}

// single-pass bandsel (VALID ONLY because band_n ~2k at DELTA=1e-4 — per-item same-address
// atomics; R10 showed this design explodes at band_n ~40k). Level-2 selection inlined.
__global__ void bandsel_kernel(const float* __restrict__ probs_b, const int* __restrict__ E,
                               const uint2* __restrict__ vj,
                               const unsigned int* __restrict__ hist,
                               SelState* __restrict__ st,
                               unsigned int* __restrict__ band_p, unsigned int* __restrict__ band_j,
                               unsigned int* __restrict__ band_e, unsigned int* __restrict__ band_v) {
    __shared__ unsigned int csum[256];
    __shared__ unsigned int sres[2];
    __shared__ unsigned int whi[4];
    unsigned int B1, rem1, bin2, rem2_unused;
    radix_sel_256(hist, (unsigned int)K_KEEP, csum, sres, B1, rem1);
    radix_sel_256(hist + 2048, rem1, csum, sres, bin2, rem2_unused);
    unsigned int P = (B1 << 21) | (bin2 << 10);
    float lo = __uint_as_float(P) - DELTA;
    float hi = __uint_as_float(P + 1024u) + DELTA;
    if (threadIdx.x == 0) { st->lo_edge = lo; st->hi_edge = hi; }
    unsigned int nhi = 0;
    for (unsigned int p = blockIdx.x * 256 + threadIdx.x; p < NNZ; p += gridDim.x * 256) {
        float pk = probs_b[p];
        if (pk > hi) nhi++;
        else if (pk >= lo) {
            unsigned int s = atomicAdd(&st->band_n, 1u);
            if (s < BANDCAP) {
                uint2 t = vj[p];
                band_p[s] = p;
                band_j[s] = t.y;
                band_e[s] = (unsigned int)E[t.y];
                band_v[s] = t.x;
            }
        }
    }
    #pragma unroll
    for (int o = 32; o > 0; o >>= 1) nhi += __shfl_down(nhi, o);
    if ((threadIdx.x & 63) == 0) whi[threadIdx.x >> 6] = nhi;
    __syncthreads();
    if (threadIdx.x == 0) {
        unsigned int th = whi[0] + whi[1] + whi[2] + whi[3];
        if (th) atomicAdd(&st->n_hi, th);
    }
}

// exact f64 recompute for band members; W1 staged in LDS; bhist1 inlined (lane k==0 bins
// its freshly computed key).
__global__ void rescue_kernel(const uint2* __restrict__ vj,
                              const unsigned int* __restrict__ edge_off,
                              const float* __restrict__ x, const float* __restrict__ W1,
                              const float* __restrict__ b1, const float* __restrict__ W2,
                              const float* __restrict__ b2,
                              const unsigned int* __restrict__ band_e,
                              const unsigned int* __restrict__ band_v,
                              const SelState* __restrict__ st,
                              unsigned long long* __restrict__ band_key,
                              unsigned int* __restrict__ hist) {
    unsigned int n = st->band_n; if (n > BANDCAP) n = BANDCAP;
    if (blockIdx.x * 8 >= n) return;
    __shared__ float sW[128 * 32];
    for (int t = threadIdx.x; t < 128 * 32; t += 256) sW[t] = W1[t];
    __syncthreads();
    unsigned int g = blockIdx.x * 8 + (threadIdx.x >> 5);
    if (g >= n) return;
    int k = threadIdx.x & 31;
    unsigned int v = band_v[g];
    unsigned int e = band_e[g];
    unsigned int off = edge_off[e];
    unsigned int deg = edge_off[e + 1] - off;

    const float* xv = x + (size_t)v * 64u;
    double a = 0.0;
    #pragma unroll 8
    for (int d = 0; d < 64; ++d) a += (double)xv[d] * (double)sW[d * 32 + k];
    double bsum = 0.0;
    for (unsigned int m = off; m < off + deg; ++m) {
        const float* xm = x + (size_t)vj[m].x * 64u;
        double acc = 0.0;
        #pragma unroll 8
        for (int d = 0; d < 64; ++d) acc += (double)xm[d] * (double)sW[(64 + d) * 32 + k];
        bsum += acc;
    }
    double cc = (double)(deg > 1u ? deg : 1u);
    double h = a + bsum / cc + (double)b1[k];
    h = h > 0.0 ? h : 0.0;
    double t = h * (double)W2[k];
    #pragma unroll
    for (int o = 16; o > 0; o >>= 1) t += __shfl_down(t, o, 32);
    if (k == 0) {
        double pr = 1.0 / (1.0 + exp(-(t + (double)b2[0])));
        band_key[g] = (unsigned long long)__double_as_longlong(pr);
        unsigned int u = band_u32(pr, st->lo_edge);
        atomicAdd(&hist[4096 + (u >> 21)], 1u);   // inlined bhist1
    }
}

// band level-1 selection inlined.
__global__ void bhist2_kernel(const unsigned long long* __restrict__ band_key,
                              const SelState* __restrict__ st, unsigned int* __restrict__ hist) {
    __shared__ unsigned int csum[256];
    __shared__ unsigned int sres[2];
    __shared__ unsigned int lh[2048];
    unsigned int bB1, rem_unused;
    radix_sel_256(hist + 4096, (unsigned int)K_KEEP - st->n_hi, csum, sres, bB1, rem_unused);
    for (int t = threadIdx.x; t < 2048; t += 256) lh[t] = 0;
    __syncthreads();
    unsigned int n = st->band_n; if (n > BANDCAP) n = BANDCAP;
    float lo = st->lo_edge;
    for (unsigned int i = blockIdx.x * 256 + threadIdx.x; i < n; i += gridDim.x * 256) {
        unsigned int u = band_u32(__longlong_as_double((long long)band_key[i]), lo);
        if ((u >> 21) == bB1) atomicAdd(&lh[(u >> 10) & 2047u], 1u);
    }
    __syncthreads();
    for (int t = threadIdx.x; t < 2048; t += 256)
        if (lh[t]) atomicAdd(&hist[6144 + t], lh[t]);
}

// both band scans inlined; block 0 persists bU0/brem2 for btierank; blocks beyond band_n
// early-exit before the radix preambles.
__global__ void btie_kernel(const unsigned long long* __restrict__ band_key,
                            const unsigned int* __restrict__ band_j,
                            const unsigned int* __restrict__ band_p,
                            const unsigned int* __restrict__ hist,
                            SelState* __restrict__ st, unsigned char* __restrict__ flag,
                            unsigned long long* __restrict__ tie_k,
                            unsigned int* __restrict__ tie_j, unsigned int* __restrict__ tie_p) {
    unsigned int n = st->band_n; if (n > BANDCAP) n = BANDCAP;
    if (blockIdx.x != 0 && blockIdx.x * 256u >= n) return;   // uniform early-exit
    __shared__ unsigned int csum[256];
    __shared__ unsigned int sres[2];
    unsigned int bB1, brem1, bin2, brem2;
    radix_sel_256(hist + 4096, (unsigned int)K_KEEP - st->n_hi, csum, sres, bB1, brem1);
    radix_sel_256(hist + 6144, brem1, csum, sres, bin2, brem2);
    unsigned int U0 = (bB1 << 21) | (bin2 << 10);
    if (blockIdx.x == 0 && threadIdx.x == 0) { st->bU0 = U0; st->brem2 = brem2; }
    unsigned int i = blockIdx.x * 256 + threadIdx.x;
    if (i >= n) return;
    float lo = st->lo_edge;
    unsigned long long key = band_key[i];
    unsigned int u = band_u32(__longlong_as_double((long long)key), lo);
    if (u >= U0 + 1024u) {
        flag[band_p[i]] = 2u;
    } else if (u >= U0) {
        unsigned int s = atomicAdd(&st->tie_n, 1u);
        if (s < TIECAP) { tie_k[s] = key; tie_j[s] = band_j[i]; tie_p[s] = band_p[i]; }
    }
}

// exact rank inside the (tiny) tie bucket by (key desc, j asc); take first brem2
__global__ void btierank_kernel(const unsigned long long* __restrict__ tie_k,
                                const unsigned int* __restrict__ tie_j,
                                const unsigned int* __restrict__ tie_p,
                                const SelState* __restrict__ st, unsigned char* __restrict__ flag) {
    unsigned int n = st->tie_n; if (n > TIECAP) n = TIECAP;
    unsigned int need = st->brem2;
    for (unsigned int i = threadIdx.x; i < n; i += 256) {
        unsigned long long ki = tie_k[i];
        unsigned int ji = tie_j[i];
        unsigned int r = 0;
        for (unsigned int q = 0; q < n; ++q) {
            unsigned long long kq = tie_k[q];
            if (kq > ki || (kq == ki && tie_j[q] < ji)) r++;
        }
        if (r < need) flag[tie_p[i]] = 2u;
    }
}

// fused outputs: blocks [0,OUT) j-order incidence outputs (4 j's/thread, float4);
// blocks [OUT, OUT+EOUT) per-edge outputs.
__global__ void outs_kernel(const float* __restrict__ probs_b, const unsigned char* __restrict__ flag,
                            const int* __restrict__ E, const unsigned int* __restrict__ rank,
                            const unsigned int* __restrict__ edge_off,
                            const SelState* __restrict__ st,
                            float* __restrict__ o_probs, float* __restrict__ o_soft,
                            float* __restrict__ o_hard,
                            float* __restrict__ o_es, float* __restrict__ o_eh) {
    float hi = st->hi_edge;
    if (blockIdx.x < OUT_BLOCKS) {
        unsigned int j0 = (blockIdx.x * 256 + threadIdx.x) * 4u;
        if (j0 >= NNZ) return;   // NNZ % 4 == 0
        int4  e4 = *reinterpret_cast<const int4*>(E + j0);
        uint4 r4 = *reinterpret_cast<const uint4*>(rank + j0);
        unsigned int p0 = edge_off[e4.x] + r4.x;
        unsigned int p1 = edge_off[e4.y] + r4.y;
        unsigned int p2 = edge_off[e4.z] + r4.z;
        unsigned int p3 = edge_off[e4.w] + r4.w;
        float pk0 = probs_b[p0], pk1 = probs_b[p1], pk2 = probs_b[p2], pk3 = probs_b[p3];
        unsigned char f0 = flag[p0], f1 = flag[p1], f2 = flag[p2], f3 = flag[p3];
        float4 pr = make_float4(pk0, pk1, pk2, pk3);
        float4 hb = make_float4((pk0 > hi || f0 == 2u) ? 1.f : 0.f,
                                (pk1 > hi || f1 == 2u) ? 1.f : 0.f,
                                (pk2 > hi || f2 == 2u) ? 1.f : 0.f,
                                (pk3 > hi || f3 == 2u) ? 1.f : 0.f);
        *reinterpret_cast<float4*>(o_probs + j0) = pr;
        *reinterpret_cast<float4*>(o_soft  + j0) = hb;
        *reinterpret_cast<float4*>(o_hard  + j0) = hb;
    } else {
        unsigned int e = (blockIdx.x - OUT_BLOCKS) * 256 + threadIdx.x;
        if (e >= N_EDGES) return;
        unsigned int off = edge_off[e];
        unsigned int deg = edge_off[e + 1] - off;
        unsigned int cnt = 0;
        for (unsigned int i = 0; i < deg; ++i)
            cnt += (probs_b[off + i] > hi || flag[off + i] == 2u) ? 1u : 0u;
        float cc = (float)(deg > 1u ? deg : 1u);
        o_es[e] = (float)cnt / cc;
        o_eh[e] = cnt ? 1.f : 0.f;
    }
}

extern "C" void kernel_launch(void* const* d_in, const int* in_sizes, int n_in,
                              void* d_out, int out_size, void* d_ws, size_t ws_size,
                              hipStream_t stream) {
    const float* x  = (const float*)d_in[0];
    const int*   V  = (const int*)d_in[1];
    const int*   E  = (const int*)d_in[2];
    const float* W1 = (const float*)d_in[3];
    const float* b1 = (const float*)d_in[4];
    const float* W2 = (const float*)d_in[5];
    const float* b2 = (const float*)d_in[6];

    float* out     = (float*)d_out;
    float* o_probs = out;
    float* o_soft  = out + NNZ;
    float* o_hard  = out + 2 * (size_t)NNZ;
    float* o_ep    = out + 3 * (size_t)NNZ;
    float* o_es    = out + 3 * (size_t)NNZ + N_EDGES;
    float* o_eh    = out + 3 * (size_t)NNZ + 2 * (size_t)N_EDGES;

    char* w = (char*)d_ws;
    float2*             p_ab2    = (float2*)(w + OFF_PAB);
    float*              probs_b  = (float*)(w + OFF_PB32);
    uint2*              vj       = (uint2*)(w + OFF_VJ);
    unsigned int*       rank     = (unsigned int*)(w + OFF_RANK);
    unsigned int*       edge_off = (unsigned int*)(w + OFF_EOFF);
    unsigned int*       bsums    = (unsigned int*)(w + OFF_BS);
    unsigned int*       band_p   = (unsigned int*)(w + OFF_BANDP);
    unsigned int*       band_j   = (unsigned int*)(w + OFF_BANDJ);
    unsigned int*       band_e   = (unsigned int*)(w + OFF_BANDE);
    unsigned int*       band_v   = (unsigned int*)(w + OFF_BANDV);
    unsigned long long* band_key = (unsigned long long*)(w + OFF_BANDK);
    unsigned long long* tie_k    = (unsigned long long*)(w + OFF_TIEK);
    unsigned int*       tie_j    = (unsigned int*)(w + OFF_TIEJ);
    unsigned int*       tie_p    = (unsigned int*)(w + OFF_TIEP);
    unsigned char*      flag     = (unsigned char*)(w + OFF_FLAG);
    unsigned int*       edge_cnt = (unsigned int*)(w + OFF_ECNT);
    unsigned int*       hist     = (unsigned int*)(w + OFF_HIST);
    SelState*           st       = (SelState*)(w + OFF_ST);

    hipMemsetAsync(w + ZERO_OFF, 0, ZERO_LEN, stream);

    proj_count_kernel<<<CNT_BLOCKS + PROJ_BLOCKS, 256, 0, stream>>>(x, W1, p_ab2, E, edge_cnt, rank);
    scanA_kernel<<<SCAN_BLOCKS, 256, 0, stream>>>(edge_cnt, edge_off, bsums);
    scanC_kernel<<<(N_EDGES + 255) / 256, 256, 0, stream>>>(edge_off, bsums);
    scatter_kernel<<<SC_BLOCKS, 256, 0, stream>>>(V, E, edge_off, rank, vj);

    edge_logit_kernel<<<(N_EDGES + 3) / 4, 256, 0, stream>>>(vj, edge_off,
                                                             p_ab2, b1, W2, b2, probs_b, o_ep);

    hist1_kernel<<<1024, 256, 0, stream>>>(probs_b, hist);
    hist2_kernel<<<1024, 256, 0, stream>>>(probs_b, hist, hist);
    bandsel_kernel<<<1024, 256, 0, stream>>>(probs_b, E, vj, hist, st,
                                             band_p, band_j, band_e, band_v);
    rescue_kernel<<<BANDCAP / 8, 256, 0, stream>>>(vj, edge_off, x, W1, b1, W2, b2,
                                                   band_e, band_v, st, band_key, hist);

    bhist2_kernel<<<64, 256, 0, stream>>>(band_key, st, hist);
    btie_kernel<<<BANDCAP / 256, 256, 0, stream>>>(band_key, band_j, band_p, hist, st, flag,
                                                   tie_k, tie_j, tie_p);
    btierank_kernel<<<1, 256, 0, stream>>>(tie_k, tie_j, tie_p, st, flag);

    outs_kernel<<<OUT_BLOCKS + EOUT_BLOCKS, 256, 0, stream>>>(probs_b, flag, E, rank, edge_off,
                                                              st, o_probs, o_soft, o_hard,
                                                              o_es, o_eh);
}